// Round 2
// baseline (7939.298 us; speedup 1.0000x reference)
//
#include <hip/hip_runtime.h>
#include <hip/hip_cooperative_groups.h>
#include <math.h>

namespace cg = cooperative_groups;

namespace {

constexpr int B = 16, C = 128, H = 64, W = 64;
constexpr int T = W + H - 1;   // 127 diagonal steps
constexpr int VSTR = 388;      // v row stride in floats (bank decorrelation, 16B-aligned)

// x [B][C][H][W] -> xT [B][H][W][C]
__global__ void transpose_x(const float* __restrict__ x, float* __restrict__ xT) {
    __shared__ float tile[C][W + 1];
    int b = blockIdx.x >> 6, row = blockIdx.x & 63;
    int tid = threadIdx.x;
#pragma unroll
    for (int i = 0; i < (C * W) / 256; ++i) {
        int idx = i * 256 + tid;
        int c = idx >> 6, w = idx & 63;
        tile[c][w] = x[((b * C + c) * H + row) * W + w];
    }
    __syncthreads();
#pragma unroll
    for (int i = 0; i < (C * W) / 256; ++i) {
        int idx = i * 256 + tid;
        int w = idx >> 7, c = idx & 127;
        xT[((b * H + row) * W + w) * C + c] = tile[c][w];
    }
}

// Persistent diagonal-LSTM. Grid: 256 blocks = 32 pos-groups x 8 out-groups.
// Block out-group og owns channels [og*16, og*16+16) x 4 gates; weights stay in LDS
// for the whole scan. Each step, active positions (trapezoid) are rebalanced across
// the 32 pos-groups; grid.sync() separates steps.
__global__ __launch_bounds__(256) void lstm_persist(
        const float* __restrict__ xT,
        const float* __restrict__ w_is, const float* __restrict__ b_is,
        const float* __restrict__ w_ss, const float* __restrict__ b_ss,
        float* __restrict__ hA, float* __restrict__ hB,
        float* __restrict__ c_buf, float* __restrict__ hist) {

    __shared__ float4 w4[16][385];     // [ch][k] = (o,f,i,g) weights, 96.25 KB
    __shared__ float  v[32][VSTR];     // [local pos][x(128)|h_shift(128)|h(128)] 48.5 KB

    const int og = blockIdx.x & 7;
    const int pg = blockIdx.x >> 3;
    const int tid = threadIdx.x;

    // ---- one-time: load this block's weight slice, gate-interleaved ----
    for (int i = tid; i < 16 * 384; i += 256) {
        int ch = i / 384;
        int k  = i - ch * 384;
        int cgl = og * 16 + ch;
        float4 wv;
        float* pw = reinterpret_cast<float*>(&wv);
#pragma unroll
        for (int g = 0; g < 4; ++g) {
            int row = g * 128 + cgl;
            float val;
            if (k < 128)      val = w_is[row * 128 + k];
            else if (k < 256) val = w_ss[(row * 128 + (k - 128)) * 2 + 0];
            else              val = w_ss[(row * 128 + (k - 256)) * 2 + 1];
            pw[g] = val;
        }
        w4[ch][k] = wv;
    }

    const int ch  = tid & 15;          // channel within out-group
    const int pp  = tid >> 4;          // pos-pair index 0..15
    const int cgl = og * 16 + ch;      // absolute channel
    float4 bias;
    bias.x = b_is[cgl]           + b_ss[cgl];
    bias.y = b_is[C + cgl]       + b_ss[C + cgl];
    bias.z = b_is[2 * C + cgl]   + b_ss[2 * C + cgl];
    bias.w = b_is[3 * C + cgl]   + b_ss[3 * C + cgl];

    const int sp = tid >> 3;           // staging pos 0..31
    const int sc = tid & 7;            // staging chunk 0..7

    cg::grid_group grid = cg::this_grid();
    __syncthreads();                   // weights ready (block-local)

    for (int t = 0; t < T; ++t) {
        const float* __restrict__ hp = (t & 1) ? hB : hA;
        float* __restrict__ hc       = (t & 1) ? hA : hB;
        const int lo  = (t > H - 1) ? (t - (H - 1)) : 0;   // active rows [lo, hi]
        const int hi  = (t < W - 1) ? t : (W - 1) + (t - (W - 1)) * 0;  // min(t, 63)
        const int hi2 = (t < H - 1) ? t : H - 1;
        (void)hi;
        const int cnt  = hi2 - lo + 1;
        const int P    = B * cnt;                 // total active positions
        const int m    = (P + 31) >> 5;           // positions per pos-group
        const int base = pg * m;
        const int nloc = min(m, P - base);        // may be <=0

        // ---- stage v = [x | h_shift | h] for this block's active positions ----
        if (sp < nloc) {
            const int slot = base + sp;
            const int b    = slot / cnt;
            const int row  = lo + (slot - b * cnt);
            const float* xs = &xT[((size_t)((b * H + row) * W) + (t - row)) * C];
            const float* hh = &hp[(size_t)(b * H + row) * C];
            const float* hs = &hp[(size_t)(b * H + row - 1) * C];
            const bool has  = (row > 0);
#pragma unroll
            for (int j = 0; j < 4; ++j) {
                const int k4 = sc + 8 * j;        // coalesced 128B per 8 lanes
                *(float4*)&v[sp][k4 * 4]         = *(const float4*)&xs[k4 * 4];
                float4 hv = has ? *(const float4*)&hs[k4 * 4]
                                : make_float4(0.f, 0.f, 0.f, 0.f);
                *(float4*)&v[sp][C + k4 * 4]     = hv;
                *(float4*)&v[sp][2 * C + k4 * 4] = *(const float4*)&hh[k4 * 4];
            }
        }
        __syncthreads();

        // ---- compute: 2 positions x 1 channel x 4 gates per thread ----
        const int p0 = pp * 2;
        if (p0 < nloc) {
            const bool two = (p0 + 1) < nloc;
            float4 a0 = bias, a1 = bias;
            const float* vp0 = v[p0];
            const float* vp1 = v[p0 + 1];
#pragma unroll 4
            for (int k4 = 0; k4 < 96; ++k4) {
                const float4 va = *(const float4*)&vp0[k4 * 4];
                const float4 vb = *(const float4*)&vp1[k4 * 4];
                const float4 w0 = w4[ch][k4 * 4 + 0];
                const float4 w1 = w4[ch][k4 * 4 + 1];
                const float4 w2 = w4[ch][k4 * 4 + 2];
                const float4 w3 = w4[ch][k4 * 4 + 3];
                a0.x += w0.x * va.x + w1.x * va.y + w2.x * va.z + w3.x * va.w;
                a0.y += w0.y * va.x + w1.y * va.y + w2.y * va.z + w3.y * va.w;
                a0.z += w0.z * va.x + w1.z * va.y + w2.z * va.z + w3.z * va.w;
                a0.w += w0.w * va.x + w1.w * va.y + w2.w * va.z + w3.w * va.w;
                a1.x += w0.x * vb.x + w1.x * vb.y + w2.x * vb.z + w3.x * vb.w;
                a1.y += w0.y * vb.x + w1.y * vb.y + w2.y * vb.z + w3.y * vb.w;
                a1.z += w0.z * vb.x + w1.z * vb.y + w2.z * vb.z + w3.z * vb.w;
                a1.w += w0.w * vb.x + w1.w * vb.y + w2.w * vb.z + w3.w * vb.w;
            }
            {
                const int slot = base + p0;
                const int b    = slot / cnt;
                const int row  = lo + (slot - b * cnt);
                const size_t idx = (size_t)(b * H + row) * C + cgl;
                float o_ = 1.f / (1.f + __expf(-a0.x));
                float f_ = 1.f / (1.f + __expf(-a0.y));
                float i_ = 1.f / (1.f + __expf(-a0.z));
                float g_ = tanhf(a0.w);
                float cn = f_ * c_buf[idx] + i_ * g_;
                c_buf[idx] = cn;
                float hn = o_ * tanhf(cn);
                hc[idx] = hn;
                hist[((size_t)((b * H + row) * W) + (t - row)) * C + cgl] = hn;
            }
            if (two) {
                const int slot = base + p0 + 1;
                const int b    = slot / cnt;
                const int row  = lo + (slot - b * cnt);
                const size_t idx = (size_t)(b * H + row) * C + cgl;
                float o_ = 1.f / (1.f + __expf(-a1.x));
                float f_ = 1.f / (1.f + __expf(-a1.y));
                float i_ = 1.f / (1.f + __expf(-a1.z));
                float g_ = tanhf(a1.w);
                float cn = f_ * c_buf[idx] + i_ * g_;
                c_buf[idx] = cn;
                float hn = o_ * tanhf(cn);
                hc[idx] = hn;
                hist[((size_t)((b * H + row) * W) + (t - row)) * C + cgl] = hn;
            }
        }
        __threadfence();
        grid.sync();
    }
}

// hist [B][H][W][C] -> out [B][C][H][W]
__global__ void unhist(const float* __restrict__ hist, float* __restrict__ out) {
    __shared__ float tile[W][C + 1];
    int b = blockIdx.x >> 6, row = blockIdx.x & 63;
    int tid = threadIdx.x;
#pragma unroll
    for (int i = 0; i < (C * W) / 256; ++i) {
        int idx = i * 256 + tid;
        int w = idx >> 7, c = idx & 127;
        tile[w][c] = hist[((size_t)(b * H + row) * W + w) * C + c];
    }
    __syncthreads();
#pragma unroll
    for (int i = 0; i < (C * W) / 256; ++i) {
        int idx = i * 256 + tid;
        int c = idx >> 6, w = idx & 63;
        out[((size_t)(b * C + c) * H + row) * W + w] = tile[w][c];
    }
}

} // namespace

extern "C" void kernel_launch(void* const* d_in, const int* in_sizes, int n_in,
                              void* d_out, int out_size, void* d_ws, size_t ws_size,
                              hipStream_t stream) {
    const float* x    = (const float*)d_in[0];
    const float* w_is = (const float*)d_in[1];
    const float* b_is = (const float*)d_in[2];
    const float* w_ss = (const float*)d_in[3];
    const float* b_ss = (const float*)d_in[4];
    float* out = (float*)d_out;

    float* wsf  = (float*)d_ws;
    float* xT   = wsf;                                  // B*H*W*C = 8M floats
    float* hist = xT + (size_t)B * H * W * C;           // 8M floats
    float* hA   = hist + (size_t)B * H * W * C;         // B*H*C
    float* hB   = hA + (size_t)B * H * C;
    float* cb   = hB + (size_t)B * H * C;

    hipLaunchKernelGGL(transpose_x, dim3(B * H), dim3(256), 0, stream, x, xT);
    hipMemsetAsync(hA, 0, (size_t)B * H * C * sizeof(float), stream);
    hipMemsetAsync(hB, 0, (size_t)B * H * C * sizeof(float), stream);
    hipMemsetAsync(cb, 0, (size_t)B * H * C * sizeof(float), stream);

    void* args[] = { (void*)&xT, (void*)&w_is, (void*)&b_is, (void*)&w_ss,
                     (void*)&b_ss, (void*)&hA, (void*)&hB, (void*)&cb, (void*)&hist };
    hipLaunchCooperativeKernel((const void*)lstm_persist, dim3(256), dim3(256),
                               args, 0, stream);

    hipLaunchKernelGGL(unhist, dim3(B * H), dim3(256), 0, stream, hist, out);
}

// Round 3
// 2781.659 us; speedup vs baseline: 2.8542x; 2.8542x over previous
//
#include <hip/hip_runtime.h>
#include <math.h>

namespace {

constexpr int B = 16, C = 128, H = 64, W = 64;
constexpr int T = W + H - 1;   // 127 diagonal steps
constexpr int VSTR = 388;      // v row stride in floats (16B aligned)

// x [B][C][H][W] -> xT [B][H][W][C]
__global__ void transpose_x(const float* __restrict__ x, float* __restrict__ xT) {
    __shared__ float tile[C][W + 1];
    int b = blockIdx.x >> 6, row = blockIdx.x & 63;
    int tid = threadIdx.x;
#pragma unroll
    for (int i = 0; i < (C * W) / 256; ++i) {
        int idx = i * 256 + tid;
        int c = idx >> 6, w = idx & 63;
        tile[c][w] = x[((b * C + c) * H + row) * W + w];
    }
    __syncthreads();
#pragma unroll
    for (int i = 0; i < (C * W) / 256; ++i) {
        int idx = i * 256 + tid;
        int w = idx >> 7, c = idx & 127;
        xT[((b * H + row) * W + w) * C + c] = tile[c][w];
    }
}

// Persistent diagonal LSTM, neighbor flag sync (no grid.sync).
// 256 blocks = 32 pos-groups (pg: rows == pg mod 32) x 8 out-groups (og: 16 ch).
// Weights live in VGPRs (96 floats/thread) for all 127 steps; c-state in registers.
// hist is write-once: h[t][b][row] == hist[b][row][t-row][:].
__global__ __launch_bounds__(256) void lstm_wave(
        const float* __restrict__ xT,
        const float* __restrict__ w_is, const float* __restrict__ b_is,
        const float* __restrict__ w_ss, const float* __restrict__ b_ss,
        float* __restrict__ hist, unsigned int* __restrict__ flags) {

    __shared__ float  v[32][VSTR];       // [slot][x(128)|h_shift(128)|h(128)]
    __shared__ float4 red[32][4][17];    // cross-wave partial sums

    const int tid  = threadIdx.x;
    const int og   = blockIdx.x & 7;
    const int pg   = blockIdx.x >> 3;
    const int pgm1 = (pg + 31) & 31;

    // ---- weights into registers: thread = (ch, kg), k-slice of 24 ----
    const int ch = tid & 15;
    const int kg = tid >> 4;             // 0..15
    const int co = og * 16 + ch;

    float wr[4][24];
#pragma unroll
    for (int g = 0; g < 4; ++g) {
        const int row = g * 128 + co;
#pragma unroll
        for (int j = 0; j < 24; ++j) {
            const int k = kg * 24 + j;
            float val;
            if (k < 128)      val = w_is[row * 128 + k];
            else if (k < 256) val = w_ss[(row * 128 + (k - 128)) * 2 + 0];
            else              val = w_ss[(row * 128 + (k - 256)) * 2 + 1];
            wr[g][j] = val;
        }
    }

    // ---- phase-B identity: thread owns 2 (slot, ch) pairs, c in registers ----
    const int sB   = tid >> 3;           // slot = b*2 + ridx
    const int chB0 = (tid & 7) * 2;
    const int bB   = sB >> 1;
    const int rowB = pg + 32 * (sB & 1);
    float creg[2] = {0.f, 0.f};
    float4 bias[2];
#pragma unroll
    for (int i = 0; i < 2; ++i) {
        const int cco = og * 16 + chB0 + i;
        bias[i].x = b_is[cco]         + b_ss[cco];
        bias[i].y = b_is[C + cco]     + b_ss[C + cco];
        bias[i].z = b_is[2 * C + cco] + b_ss[2 * C + cco];
        bias[i].w = b_is[3 * C + cco] + b_ss[3 * C + cco];
    }

    const int wv = tid >> 6;             // wave 0..3
    const int ln = tid & 63;

#pragma unroll 1
    for (int t = 0; t < T; ++t) {
        const bool act0 = (unsigned)(t - pg) < 64u;
        const bool act1 = (unsigned)(t - pg - 32) < 64u;
        const bool any  = act0 | act1;

        // ---- wait for step-(t-1) h of pg and pg-1 ----
        if (any && t > 0 && tid == 0) {
            const unsigned tgt = 8u * (unsigned)t;
            while (__hip_atomic_load(&flags[pg * 32], __ATOMIC_ACQUIRE,
                                     __HIP_MEMORY_SCOPE_AGENT) < tgt) {}
            while (__hip_atomic_load(&flags[pgm1 * 32], __ATOMIC_ACQUIRE,
                                     __HIP_MEMORY_SCOPE_AGENT) < tgt) {}
        }
        __syncthreads();   // S1: flag wait done (tid0's buffer_inv covers CU L1 + XCD L2)

        // ---- stage v: each wave fills 8 slots, contiguous 1KB per pass ----
        if (any) {
            for (int i = 0; i < 8; ++i) {
                const int s   = wv * 8 + i;
                const int row = pg + 32 * (s & 1);
                const int w   = t - row;
                if ((unsigned)w < 64u) {
                    const int b = s >> 1;
                    const size_t posbase = ((size_t)(b * H + row) * W + w) * C;
                    float4 val;
                    if (ln < 32) {
                        val = *(const float4*)&xT[posbase + ln * 4];
                    } else {
                        val = make_float4(0.f, 0.f, 0.f, 0.f);
                        if (row > 0) {
                            const size_t pb2 = ((size_t)(b * H + row - 1) * W + w) * C;
                            val = *(const float4*)&hist[pb2 + (ln - 32) * 4];
                        }
                    }
                    *(float4*)&v[s][ln * 4] = val;   // [0,256): x | h_shift
                    if (ln < 32) {
                        float4 hv = make_float4(0.f, 0.f, 0.f, 0.f);
                        if (w > 0) hv = *(const float4*)&hist[posbase - C + ln * 4];
                        *(float4*)&v[s][256 + ln * 4] = hv;  // h_prev
                    }
                }
            }
        }
        __syncthreads();   // S2: v ready

        // ---- phase A: partial dots, weights from registers ----
        if (any) {
#pragma unroll 2
            for (int s = 0; s < 32; ++s) {
                const int row = pg + 32 * (s & 1);
                if ((unsigned)(t - row) >= 64u) continue;
                float4 a = make_float4(0.f, 0.f, 0.f, 0.f);
                const float* vp = &v[s][kg * 24];
#pragma unroll
                for (int j4 = 0; j4 < 6; ++j4) {
                    const float4 vv = *(const float4*)&vp[j4 * 4];
                    a.x += wr[0][j4*4+0]*vv.x + wr[0][j4*4+1]*vv.y + wr[0][j4*4+2]*vv.z + wr[0][j4*4+3]*vv.w;
                    a.y += wr[1][j4*4+0]*vv.x + wr[1][j4*4+1]*vv.y + wr[1][j4*4+2]*vv.z + wr[1][j4*4+3]*vv.w;
                    a.z += wr[2][j4*4+0]*vv.x + wr[2][j4*4+1]*vv.y + wr[2][j4*4+2]*vv.z + wr[2][j4*4+3]*vv.w;
                    a.w += wr[3][j4*4+0]*vv.x + wr[3][j4*4+1]*vv.y + wr[3][j4*4+2]*vv.z + wr[3][j4*4+3]*vv.w;
                }
                // reduce over kg&3 (lane strides 16, 32)
                a.x += __shfl_xor(a.x, 16); a.y += __shfl_xor(a.y, 16);
                a.z += __shfl_xor(a.z, 16); a.w += __shfl_xor(a.w, 16);
                a.x += __shfl_xor(a.x, 32); a.y += __shfl_xor(a.y, 32);
                a.z += __shfl_xor(a.z, 32); a.w += __shfl_xor(a.w, 32);
                if (ln < 16) red[s][wv][ln] = a;
            }
        }
        __syncthreads();   // S3: red ready

        // ---- phase B: final sum + gates + c/h update + write-through h ----
        if (any && (unsigned)(t - rowB) < 64u) {
            const int w = t - rowB;
            const size_t posbase = ((size_t)(bB * H + rowB) * W + w) * C;
#pragma unroll
            for (int i = 0; i < 2; ++i) {
                const int chh = chB0 + i;
                const float4 r0 = red[sB][0][chh];
                const float4 r1 = red[sB][1][chh];
                const float4 r2 = red[sB][2][chh];
                const float4 r3 = red[sB][3][chh];
                float4 a;
                a.x = r0.x + r1.x + r2.x + r3.x + bias[i].x;
                a.y = r0.y + r1.y + r2.y + r3.y + bias[i].y;
                a.z = r0.z + r1.z + r2.z + r3.z + bias[i].z;
                a.w = r0.w + r1.w + r2.w + r3.w + bias[i].w;
                const float o_ = 1.f / (1.f + __expf(-a.x));
                const float f_ = 1.f / (1.f + __expf(-a.y));
                const float i_ = 1.f / (1.f + __expf(-a.z));
                const float g_ = tanhf(a.w);
                creg[i] = f_ * creg[i] + i_ * g_;
                const float hn = o_ * tanhf(creg[i]);
                __hip_atomic_store(&hist[posbase + og * 16 + chh], hn,
                                   __ATOMIC_RELAXED, __HIP_MEMORY_SCOPE_AGENT);
            }
        }
        __syncthreads();   // S4: all h stores retired (waitcnt before barrier)
        if (tid == 0)
            __hip_atomic_fetch_add(&flags[pg * 32], 1u, __ATOMIC_RELEASE,
                                   __HIP_MEMORY_SCOPE_AGENT);
    }
}

// hist [B][H][W][C] -> out [B][C][H][W]
__global__ void unhist(const float* __restrict__ hist, float* __restrict__ out) {
    __shared__ float tile[W][C + 1];
    int b = blockIdx.x >> 6, row = blockIdx.x & 63;
    int tid = threadIdx.x;
#pragma unroll
    for (int i = 0; i < (C * W) / 256; ++i) {
        int idx = i * 256 + tid;
        int w = idx >> 7, c = idx & 127;
        tile[w][c] = hist[((size_t)(b * H + row) * W + w) * C + c];
    }
    __syncthreads();
#pragma unroll
    for (int i = 0; i < (C * W) / 256; ++i) {
        int idx = i * 256 + tid;
        int c = idx >> 6, w = idx & 63;
        out[((size_t)(b * C + c) * H + row) * W + w] = tile[w][c];
    }
}

} // namespace

extern "C" void kernel_launch(void* const* d_in, const int* in_sizes, int n_in,
                              void* d_out, int out_size, void* d_ws, size_t ws_size,
                              hipStream_t stream) {
    const float* x    = (const float*)d_in[0];
    const float* w_is = (const float*)d_in[1];
    const float* b_is = (const float*)d_in[2];
    const float* w_ss = (const float*)d_in[3];
    const float* b_ss = (const float*)d_in[4];
    float* out = (float*)d_out;

    float* wsf  = (float*)d_ws;
    float* xT   = wsf;                                  // B*H*W*C floats
    float* hist = xT + (size_t)B * H * W * C;           // B*H*W*C floats
    unsigned int* flags = (unsigned int*)(hist + (size_t)B * H * W * C);  // 32*32 u32

    hipLaunchKernelGGL(transpose_x, dim3(B * H), dim3(256), 0, stream, x, xT);
    hipMemsetAsync(flags, 0, 32 * 32 * sizeof(unsigned int), stream);

    void* args[] = { (void*)&xT, (void*)&w_is, (void*)&b_is, (void*)&w_ss,
                     (void*)&b_ss, (void*)&hist, (void*)&flags };
    hipLaunchCooperativeKernel((const void*)lstm_wave, dim3(256), dim3(256),
                               args, 0, stream);

    hipLaunchKernelGGL(unhist, dim3(B * H), dim3(256), 0, stream, hist, out);
}

// Round 6
// 2318.036 us; speedup vs baseline: 3.4250x; 1.2000x over previous
//
#include <hip/hip_runtime.h>
#include <math.h>

namespace {

constexpr int B = 16, C = 128, H = 64, W = 64;
constexpr int T = W + H - 1;   // 127 diagonal steps
constexpr int VSTR = 388;      // v row stride in floats

// x [B][C][H][W] -> xT [B][H][W][C]
__global__ void transpose_x(const float* __restrict__ x, float* __restrict__ xT) {
    __shared__ float tile[C][W + 1];
    int b = blockIdx.x >> 6, row = blockIdx.x & 63;
    int tid = threadIdx.x;
#pragma unroll
    for (int i = 0; i < (C * W) / 256; ++i) {
        int idx = i * 256 + tid;
        int c = idx >> 6, w = idx & 63;
        tile[c][w] = x[((b * C + c) * H + row) * W + w];
    }
    __syncthreads();
#pragma unroll
    for (int i = 0; i < (C * W) / 256; ++i) {
        int idx = i * 256 + tid;
        int w = idx >> 7, c = idx & 127;
        xT[((b * H + row) * W + w) * C + c] = tile[c][w];
    }
}

// Persistent diagonal LSTM. 256 blocks = 32 pg x 8 og, 512 threads = 8 waves.
// Waves 0-3 compute slots 0-15, waves 4-7 slots 16-31 (2 waves/SIMD for latency hiding).
// Single-writer cacheline-padded flags; 16-lane parallel poll; x prefetched before poll.
__global__ __launch_bounds__(512) void lstm_wave(
        const float* __restrict__ xT,
        const float* __restrict__ w_is, const float* __restrict__ b_is,
        const float* __restrict__ w_ss, const float* __restrict__ b_ss,
        float* __restrict__ hist, unsigned int* __restrict__ flags) {

    __shared__ float  v[32][VSTR];       // [slot][x(128)|h_shift(128)|h(128)]
    __shared__ float4 red[32][4][17];    // per-slot cross-wave partials

    const int tid  = threadIdx.x;
    const int og   = blockIdx.x & 7;
    const int pg   = blockIdx.x >> 3;
    const int pgm1 = (pg + 31) & 31;

    // ---- weights into registers: (ch, kg) = (tid&15, (tid>>4)&15), 24-float K slice ----
    const int ch = tid & 15;
    const int kg = (tid >> 4) & 15;
    const int co = og * 16 + ch;

    float wr[4][24];
#pragma unroll
    for (int g = 0; g < 4; ++g) {
        const int row = g * 128 + co;
#pragma unroll
        for (int j = 0; j < 24; ++j) {
            const int k = kg * 24 + j;
            float val;
            if (k < 128)      val = w_is[row * 128 + k];
            else if (k < 256) val = w_ss[(row * 128 + (k - 128)) * 2 + 0];
            else              val = w_ss[(row * 128 + (k - 256)) * 2 + 1];
            wr[g][j] = val;
        }
    }

    // ---- phase-B identity: thread owns 1 (slot, ch); c-state in a register ----
    const int sB   = tid >> 4;           // 0..31
    const int bB   = sB >> 1;
    const int rowB = pg + 32 * (sB & 1);
    float creg = 0.f;
    float4 bias;
    bias.x = b_is[co]         + b_ss[co];
    bias.y = b_is[C + co]     + b_ss[C + co];
    bias.z = b_is[2 * C + co] + b_ss[2 * C + co];
    bias.w = b_is[3 * C + co] + b_ss[3 * C + co];

    const int wave  = tid >> 6;          // 0..7
    const int ln    = tid & 63;
    const int wv    = wave & 3;          // red column
    const int shalf = (wave >> 2) * 16;  // phase-A slot base

#pragma unroll 1
    for (int t = 0; t < T; ++t) {
        const bool act0 = (unsigned)(t - pg) < 64u;
        const bool act1 = (unsigned)(t - pg - 32) < 64u;
        const bool any  = act0 | act1;

        // ---- prefetch x into registers (no flag dependency) ----
        float4 xr[4];
        if (any) {
#pragma unroll
            for (int i = 0; i < 4; ++i) {
                const int s   = wave * 4 + i;
                const int row = pg + 32 * (s & 1);
                const int w   = t - row;
                xr[i] = make_float4(0.f, 0.f, 0.f, 0.f);
                if ((unsigned)w < 64u && ln < 32) {
                    const int b = s >> 1;
                    xr[i] = *(const float4*)&xT[((size_t)((b * H + row) * W) + w) * C + ln * 4];
                }
            }
        }

        // ---- wait: parallel poll of 16 single-writer flags ----
        if (any && t > 0) {
            if (tid < 16) {
                const int qg = (tid < 8) ? pg : pgm1;
                const unsigned fidx = (unsigned)(qg * 8 + (tid & 7)) * 32u;
                while (__hip_atomic_load(&flags[fidx], __ATOMIC_RELAXED,
                                         __HIP_MEMORY_SCOPE_AGENT) < (unsigned)t) {}
            }
            __builtin_amdgcn_fence(__ATOMIC_ACQUIRE, "agent");
        }
        __syncthreads();   // S1

        // ---- stage v: wave stages slots wave*4 .. wave*4+3 ----
        if (any) {
#pragma unroll
            for (int i = 0; i < 4; ++i) {
                const int s   = wave * 4 + i;
                const int row = pg + 32 * (s & 1);
                const int w   = t - row;
                if ((unsigned)w < 64u) {
                    const int b = s >> 1;
                    const size_t posbase = ((size_t)((b * H + row) * W) + w) * C;
                    if (ln < 32) {
                        *(float4*)&v[s][ln * 4] = xr[i];                  // x
                        float4 hv = make_float4(0.f, 0.f, 0.f, 0.f);
                        if (w > 0)
                            hv = *(const float4*)&hist[posbase - C + ln * 4];
                        *(float4*)&v[s][256 + ln * 4] = hv;               // h_prev
                    } else {
                        float4 hs = make_float4(0.f, 0.f, 0.f, 0.f);
                        if (row > 0)
                            hs = *(const float4*)&hist[((size_t)((b * H + row - 1) * W) + w) * C + (ln - 32) * 4];
                        *(float4*)&v[s][ln * 4] = hs;                     // h_shift -> [128,256)
                    }
                }
            }
        }
        __syncthreads();   // S2

        // ---- phase A: 16 slots per thread, weights in registers ----
        if (any) {
#pragma unroll 2
            for (int sl = 0; sl < 16; ++sl) {
                const int s   = shalf + sl;
                const int row = pg + 32 * (s & 1);
                if ((unsigned)(t - row) >= 64u) continue;
                float4 a = make_float4(0.f, 0.f, 0.f, 0.f);
                const float* vp = &v[s][kg * 24];
#pragma unroll
                for (int j4 = 0; j4 < 6; ++j4) {
                    const float4 vv = *(const float4*)&vp[j4 * 4];
                    a.x += wr[0][j4*4+0]*vv.x + wr[0][j4*4+1]*vv.y + wr[0][j4*4+2]*vv.z + wr[0][j4*4+3]*vv.w;
                    a.y += wr[1][j4*4+0]*vv.x + wr[1][j4*4+1]*vv.y + wr[1][j4*4+2]*vv.z + wr[1][j4*4+3]*vv.w;
                    a.z += wr[2][j4*4+0]*vv.x + wr[2][j4*4+1]*vv.y + wr[2][j4*4+2]*vv.z + wr[2][j4*4+3]*vv.w;
                    a.w += wr[3][j4*4+0]*vv.x + wr[3][j4*4+1]*vv.y + wr[3][j4*4+2]*vv.z + wr[3][j4*4+3]*vv.w;
                }
                a.x += __shfl_xor(a.x, 16); a.y += __shfl_xor(a.y, 16);
                a.z += __shfl_xor(a.z, 16); a.w += __shfl_xor(a.w, 16);
                a.x += __shfl_xor(a.x, 32); a.y += __shfl_xor(a.y, 32);
                a.z += __shfl_xor(a.z, 32); a.w += __shfl_xor(a.w, 32);
                if (ln < 16) red[s][wv][ln] = a;
            }
        }
        __syncthreads();   // S3

        // ---- phase B: final sum + gates + c/h + write-through h ----
        if (any && (unsigned)(t - rowB) < 64u) {
            const int w = t - rowB;
            const size_t posbase = ((size_t)((bB * H + rowB) * W) + w) * C;
            const float4 r0 = red[sB][0][ch];
            const float4 r1 = red[sB][1][ch];
            const float4 r2 = red[sB][2][ch];
            const float4 r3 = red[sB][3][ch];
            float4 a;
            a.x = r0.x + r1.x + r2.x + r3.x + bias.x;
            a.y = r0.y + r1.y + r2.y + r3.y + bias.y;
            a.z = r0.z + r1.z + r2.z + r3.z + bias.z;
            a.w = r0.w + r1.w + r2.w + r3.w + bias.w;
            const float o_ = 1.f / (1.f + __expf(-a.x));
            const float f_ = 1.f / (1.f + __expf(-a.y));
            const float i_ = 1.f / (1.f + __expf(-a.z));
            const float g_ = tanhf(a.w);
            creg = f_ * creg + i_ * g_;
            const float hn = o_ * tanhf(creg);
            __hip_atomic_store(&hist[posbase + og * 16 + ch], hn,
                               __ATOMIC_RELAXED, __HIP_MEMORY_SCOPE_AGENT);
        }
        __syncthreads();   // S4: all stores drained (waitcnt before barrier)
        if (tid == 0)
            __hip_atomic_store(&flags[(unsigned)(pg * 8 + og) * 32u], (unsigned)(t + 1),
                               __ATOMIC_RELEASE, __HIP_MEMORY_SCOPE_AGENT);
    }
}

// hist [B][H][W][C] -> out [B][C][H][W]
__global__ void unhist(const float* __restrict__ hist, float* __restrict__ out) {
    __shared__ float tile[W][C + 1];
    int b = blockIdx.x >> 6, row = blockIdx.x & 63;
    int tid = threadIdx.x;
#pragma unroll
    for (int i = 0; i < (C * W) / 256; ++i) {
        int idx = i * 256 + tid;
        int w = idx >> 7, c = idx & 127;
        tile[w][c] = hist[((size_t)(b * H + row) * W + w) * C + c];
    }
    __syncthreads();
#pragma unroll
    for (int i = 0; i < (C * W) / 256; ++i) {
        int idx = i * 256 + tid;
        int c = idx >> 6, w = idx & 63;
        out[((size_t)(b * C + c) * H + row) * W + w] = tile[w][c];
    }
}

} // namespace

extern "C" void kernel_launch(void* const* d_in, const int* in_sizes, int n_in,
                              void* d_out, int out_size, void* d_ws, size_t ws_size,
                              hipStream_t stream) {
    const float* x    = (const float*)d_in[0];
    const float* w_is = (const float*)d_in[1];
    const float* b_is = (const float*)d_in[2];
    const float* w_ss = (const float*)d_in[3];
    const float* b_ss = (const float*)d_in[4];
    float* out = (float*)d_out;

    float* wsf  = (float*)d_ws;
    float* xT   = wsf;                                  // B*H*W*C floats
    float* hist = xT + (size_t)B * H * W * C;           // B*H*W*C floats
    unsigned int* flags = (unsigned int*)(hist + (size_t)B * H * W * C);  // 256*32 u32

    hipLaunchKernelGGL(transpose_x, dim3(B * H), dim3(256), 0, stream, x, xT);
    hipMemsetAsync(flags, 0, 256 * 32 * sizeof(unsigned int), stream);

    void* args[] = { (void*)&xT, (void*)&w_is, (void*)&b_is, (void*)&w_ss,
                     (void*)&b_ss, (void*)&hist, (void*)&flags };
    hipLaunchCooperativeKernel((const void*)lstm_wave, dim3(256), dim3(512),
                               args, 0, stream);

    hipLaunchKernelGGL(unhist, dim3(B * H), dim3(256), 0, stream, hist, out);
}

// Round 7
// 1189.640 us; speedup vs baseline: 6.6737x; 1.9485x over previous
//
#include <hip/hip_runtime.h>
#include <math.h>

namespace {

constexpr int B = 16, C = 128, H = 64, W = 64;
constexpr int T = W + H - 1;   // 127 diagonal steps
constexpr int VSTR = 388;      // v row stride in floats

// 16B coherent (agent-scope, L2-bypassing) load as two 64-bit atomics.
__device__ __forceinline__ float4 ld_h16(const float* p) {
    unsigned long long a = __hip_atomic_load((const unsigned long long*)p,
                                             __ATOMIC_RELAXED, __HIP_MEMORY_SCOPE_AGENT);
    unsigned long long b = __hip_atomic_load(((const unsigned long long*)p) + 1,
                                             __ATOMIC_RELAXED, __HIP_MEMORY_SCOPE_AGENT);
    float4 r;
    r.x = __uint_as_float((unsigned)(a & 0xffffffffu));
    r.y = __uint_as_float((unsigned)(a >> 32));
    r.z = __uint_as_float((unsigned)(b & 0xffffffffu));
    r.w = __uint_as_float((unsigned)(b >> 32));
    return r;
}

// x [B][C][H][W] -> xT [B][H][W][C]
__global__ void transpose_x(const float* __restrict__ x, float* __restrict__ xT) {
    __shared__ float tile[C][W + 1];
    int b = blockIdx.x >> 6, row = blockIdx.x & 63;
    int tid = threadIdx.x;
#pragma unroll
    for (int i = 0; i < (C * W) / 256; ++i) {
        int idx = i * 256 + tid;
        int c = idx >> 6, w = idx & 63;
        tile[c][w] = x[((b * C + c) * H + row) * W + w];
    }
    __syncthreads();
#pragma unroll
    for (int i = 0; i < (C * W) / 256; ++i) {
        int idx = i * 256 + tid;
        int w = idx >> 7, c = idx & 127;
        xT[((b * H + row) * W + w) * C + c] = tile[c][w];
    }
}

// Persistent diagonal LSTM. 256 blocks = 32 pg x 8 og, 512 threads = 8 waves.
// Fence-free producer/consumer: h + flags all agent-scope write-through atomics;
// __syncthreads drains vmcnt(0) before the relaxed flag store; consumers use
// agent-scope atomic loads (bypass stale L2). No buffer_wbl2 / buffer_inv.
__global__ __launch_bounds__(512) void lstm_wave(
        const float* __restrict__ xT,
        const float* __restrict__ w_is, const float* __restrict__ b_is,
        const float* __restrict__ w_ss, const float* __restrict__ b_ss,
        float* __restrict__ hist, unsigned int* __restrict__ flags) {

    __shared__ float  v[32][VSTR];       // [slot][x(128)|h_shift(128)|h(128)]
    __shared__ float4 red[32][4][17];    // per-slot cross-wave partials

    const int tid  = threadIdx.x;
    const int og   = blockIdx.x & 7;
    const int pg   = blockIdx.x >> 3;
    const int pgm1 = (pg + 31) & 31;

    // ---- weights into registers: (ch, kg) = (tid&15, (tid>>4)&15), 24-float K slice ----
    const int ch = tid & 15;
    const int kg = (tid >> 4) & 15;
    const int co = og * 16 + ch;

    float wr[4][24];
#pragma unroll
    for (int g = 0; g < 4; ++g) {
        const int row = g * 128 + co;
#pragma unroll
        for (int j = 0; j < 24; ++j) {
            const int k = kg * 24 + j;
            float val;
            if (k < 128)      val = w_is[row * 128 + k];
            else if (k < 256) val = w_ss[(row * 128 + (k - 128)) * 2 + 0];
            else              val = w_ss[(row * 128 + (k - 256)) * 2 + 1];
            wr[g][j] = val;
        }
    }

    // ---- phase-B identity: thread owns 1 (slot, ch); c-state in a register ----
    const int sB   = tid >> 4;           // 0..31
    const int bB   = sB >> 1;
    const int rowB = pg + 32 * (sB & 1);
    float creg = 0.f;
    float4 bias;
    bias.x = b_is[co]         + b_ss[co];
    bias.y = b_is[C + co]     + b_ss[C + co];
    bias.z = b_is[2 * C + co] + b_ss[2 * C + co];
    bias.w = b_is[3 * C + co] + b_ss[3 * C + co];

    const int wave  = tid >> 6;          // 0..7
    const int ln    = tid & 63;
    const int wv    = wave & 3;          // red column
    const int shalf = (wave >> 2) * 16;  // phase-A slot base

#pragma unroll 1
    for (int t = 0; t < T; ++t) {
        const bool act0 = (unsigned)(t - pg) < 64u;
        const bool act1 = (unsigned)(t - pg - 32) < 64u;
        const bool any  = act0 | act1;

        // ---- prefetch x into registers (no flag dependency) ----
        float4 xr[4];
        if (any) {
#pragma unroll
            for (int i = 0; i < 4; ++i) {
                const int s   = wave * 4 + i;
                const int row = pg + 32 * (s & 1);
                const int w   = t - row;
                xr[i] = make_float4(0.f, 0.f, 0.f, 0.f);
                if ((unsigned)w < 64u && ln < 32) {
                    const int b = s >> 1;
                    xr[i] = *(const float4*)&xT[((size_t)((b * H + row) * W) + w) * C + ln * 4];
                }
            }
        }

        // ---- wait: parallel poll of 16 single-writer flags (no fence) ----
        if (any && t > 0) {
            if (tid < 16) {
                const int qg = (tid < 8) ? pg : pgm1;
                const unsigned fidx = (unsigned)(qg * 8 + (tid & 7)) * 32u;
                while (__hip_atomic_load(&flags[fidx], __ATOMIC_RELAXED,
                                         __HIP_MEMORY_SCOPE_AGENT) < (unsigned)t) {}
            }
        }
        __syncthreads();   // S1

        // ---- stage v: wave stages slots wave*4 .. wave*4+3 ----
        if (any) {
#pragma unroll
            for (int i = 0; i < 4; ++i) {
                const int s   = wave * 4 + i;
                const int row = pg + 32 * (s & 1);
                const int w   = t - row;
                if ((unsigned)w < 64u) {
                    const int b = s >> 1;
                    const size_t posbase = ((size_t)((b * H + row) * W) + w) * C;
                    if (ln < 32) {
                        *(float4*)&v[s][ln * 4] = xr[i];                  // x
                        float4 hv = make_float4(0.f, 0.f, 0.f, 0.f);
                        if (w > 0)
                            hv = ld_h16(&hist[posbase - C + ln * 4]);
                        *(float4*)&v[s][256 + ln * 4] = hv;               // h_prev
                    } else {
                        float4 hs = make_float4(0.f, 0.f, 0.f, 0.f);
                        if (row > 0)
                            hs = ld_h16(&hist[((size_t)((b * H + row - 1) * W) + w) * C + (ln - 32) * 4]);
                        *(float4*)&v[s][ln * 4] = hs;                     // h_shift -> [128,256)
                    }
                }
            }
        }
        __syncthreads();   // S2

        // ---- phase A: 16 slots per thread, weights in registers ----
        if (any) {
#pragma unroll 2
            for (int sl = 0; sl < 16; ++sl) {
                const int s   = shalf + sl;
                const int row = pg + 32 * (s & 1);
                if ((unsigned)(t - row) >= 64u) continue;
                float4 a = make_float4(0.f, 0.f, 0.f, 0.f);
                const float* vp = &v[s][kg * 24];
#pragma unroll
                for (int j4 = 0; j4 < 6; ++j4) {
                    const float4 vv = *(const float4*)&vp[j4 * 4];
                    a.x += wr[0][j4*4+0]*vv.x + wr[0][j4*4+1]*vv.y + wr[0][j4*4+2]*vv.z + wr[0][j4*4+3]*vv.w;
                    a.y += wr[1][j4*4+0]*vv.x + wr[1][j4*4+1]*vv.y + wr[1][j4*4+2]*vv.z + wr[1][j4*4+3]*vv.w;
                    a.z += wr[2][j4*4+0]*vv.x + wr[2][j4*4+1]*vv.y + wr[2][j4*4+2]*vv.z + wr[2][j4*4+3]*vv.w;
                    a.w += wr[3][j4*4+0]*vv.x + wr[3][j4*4+1]*vv.y + wr[3][j4*4+2]*vv.z + wr[3][j4*4+3]*vv.w;
                }
                a.x += __shfl_xor(a.x, 16); a.y += __shfl_xor(a.y, 16);
                a.z += __shfl_xor(a.z, 16); a.w += __shfl_xor(a.w, 16);
                a.x += __shfl_xor(a.x, 32); a.y += __shfl_xor(a.y, 32);
                a.z += __shfl_xor(a.z, 32); a.w += __shfl_xor(a.w, 32);
                if (ln < 16) red[s][wv][ln] = a;
            }
        }
        __syncthreads();   // S3

        // ---- phase B: final sum + gates + c/h + write-through h ----
        if (any && (unsigned)(t - rowB) < 64u) {
            const int w = t - rowB;
            const size_t posbase = ((size_t)((bB * H + rowB) * W) + w) * C;
            const float4 r0 = red[sB][0][ch];
            const float4 r1 = red[sB][1][ch];
            const float4 r2 = red[sB][2][ch];
            const float4 r3 = red[sB][3][ch];
            float4 a;
            a.x = r0.x + r1.x + r2.x + r3.x + bias.x;
            a.y = r0.y + r1.y + r2.y + r3.y + bias.y;
            a.z = r0.z + r1.z + r2.z + r3.z + bias.z;
            a.w = r0.w + r1.w + r2.w + r3.w + bias.w;
            const float o_ = 1.f / (1.f + __expf(-a.x));
            const float f_ = 1.f / (1.f + __expf(-a.y));
            const float i_ = 1.f / (1.f + __expf(-a.z));
            const float g_ = tanhf(a.w);
            creg = f_ * creg + i_ * g_;
            const float hn = o_ * tanhf(creg);
            __hip_atomic_store(&hist[posbase + og * 16 + ch], hn,
                               __ATOMIC_RELAXED, __HIP_MEMORY_SCOPE_AGENT);
        }
        __syncthreads();   // S4: vmcnt(0) drained per-wave before barrier -> h visible
        if (tid == 0)
            __hip_atomic_store(&flags[(unsigned)(pg * 8 + og) * 32u], (unsigned)(t + 1),
                               __ATOMIC_RELAXED, __HIP_MEMORY_SCOPE_AGENT);
    }
}

// hist [B][H][W][C] -> out [B][C][H][W]
__global__ void unhist(const float* __restrict__ hist, float* __restrict__ out) {
    __shared__ float tile[W][C + 1];
    int b = blockIdx.x >> 6, row = blockIdx.x & 63;
    int tid = threadIdx.x;
#pragma unroll
    for (int i = 0; i < (C * W) / 256; ++i) {
        int idx = i * 256 + tid;
        int w = idx >> 7, c = idx & 127;
        tile[w][c] = hist[((size_t)(b * H + row) * W + w) * C + c];
    }
    __syncthreads();
#pragma unroll
    for (int i = 0; i < (C * W) / 256; ++i) {
        int idx = i * 256 + tid;
        int c = idx >> 6, w = idx & 63;
        out[((size_t)(b * C + c) * H + row) * W + w] = tile[w][c];
    }
}

} // namespace

extern "C" void kernel_launch(void* const* d_in, const int* in_sizes, int n_in,
                              void* d_out, int out_size, void* d_ws, size_t ws_size,
                              hipStream_t stream) {
    const float* x    = (const float*)d_in[0];
    const float* w_is = (const float*)d_in[1];
    const float* b_is = (const float*)d_in[2];
    const float* w_ss = (const float*)d_in[3];
    const float* b_ss = (const float*)d_in[4];
    float* out = (float*)d_out;

    float* wsf  = (float*)d_ws;
    float* xT   = wsf;                                  // B*H*W*C floats
    float* hist = xT + (size_t)B * H * W * C;           // B*H*W*C floats
    unsigned int* flags = (unsigned int*)(hist + (size_t)B * H * W * C);  // 256*32 u32

    hipLaunchKernelGGL(transpose_x, dim3(B * H), dim3(256), 0, stream, x, xT);
    hipMemsetAsync(flags, 0, 256 * 32 * sizeof(unsigned int), stream);

    void* args[] = { (void*)&xT, (void*)&w_is, (void*)&b_is, (void*)&w_ss,
                     (void*)&b_ss, (void*)&hist, (void*)&flags };
    hipLaunchCooperativeKernel((const void*)lstm_wave, dim3(256), dim3(512),
                               args, 0, stream);

    hipLaunchKernelGGL(unhist, dim3(B * H), dim3(256), 0, stream, hist, out);
}

// Round 8
// 694.208 us; speedup vs baseline: 11.4365x; 1.7137x over previous
//
#include <hip/hip_runtime.h>
#include <math.h>

namespace {

constexpr int B = 16, C = 128, H = 64, W = 64;
constexpr int T = W + H - 1;   // 127 diagonal steps
constexpr int VSL = 33;        // padded slot-dim stride (breaks 512B bank alias)

typedef short bf16x8 __attribute__((ext_vector_type(8)));
typedef float f32x4  __attribute__((ext_vector_type(4)));

// 16B coherent (agent-scope) load as two 64-bit atomics.
__device__ __forceinline__ float4 ld_h16(const float* p) {
    unsigned long long a = __hip_atomic_load((const unsigned long long*)p,
                                             __ATOMIC_RELAXED, __HIP_MEMORY_SCOPE_AGENT);
    unsigned long long b = __hip_atomic_load(((const unsigned long long*)p) + 1,
                                             __ATOMIC_RELAXED, __HIP_MEMORY_SCOPE_AGENT);
    float4 r;
    r.x = __uint_as_float((unsigned)(a & 0xffffffffu));
    r.y = __uint_as_float((unsigned)(a >> 32));
    r.z = __uint_as_float((unsigned)(b & 0xffffffffu));
    r.w = __uint_as_float((unsigned)(b >> 32));
    return r;
}

// Split float4 into truncated-bf16 hi and lo (residual) parts, write 8B each.
__device__ __forceinline__ void stw(short* hi_p, short* lo_p, int base, float4 f) {
    unsigned ua = __float_as_uint(f.x), ub = __float_as_uint(f.y);
    unsigned h0 = (ua >> 16) | (ub & 0xffff0000u);
    float ra = f.x - __uint_as_float(ua & 0xffff0000u);
    float rb = f.y - __uint_as_float(ub & 0xffff0000u);
    unsigned l0 = (__float_as_uint(ra) >> 16) | (__float_as_uint(rb) & 0xffff0000u);
    unsigned uc = __float_as_uint(f.z), ud = __float_as_uint(f.w);
    unsigned h1 = (uc >> 16) | (ud & 0xffff0000u);
    float rc = f.z - __uint_as_float(uc & 0xffff0000u);
    float rd = f.w - __uint_as_float(ud & 0xffff0000u);
    unsigned l1 = (__float_as_uint(rc) >> 16) | (__float_as_uint(rd) & 0xffff0000u);
    *(uint2*)&hi_p[base] = make_uint2(h0, h1);
    *(uint2*)&lo_p[base] = make_uint2(l0, l1);
}

// x [B][C][H][W] -> xT [B][H][W][C]
__global__ void transpose_x(const float* __restrict__ x, float* __restrict__ xT) {
    __shared__ float tile[C][W + 1];
    int b = blockIdx.x >> 6, row = blockIdx.x & 63;
    int tid = threadIdx.x;
#pragma unroll
    for (int i = 0; i < (C * W) / 256; ++i) {
        int idx = i * 256 + tid;
        int c = idx >> 6, w = idx & 63;
        tile[c][w] = x[((b * C + c) * H + row) * W + w];
    }
    __syncthreads();
#pragma unroll
    for (int i = 0; i < (C * W) / 256; ++i) {
        int idx = i * 256 + tid;
        int w = idx >> 7, c = idx & 127;
        xT[((b * H + row) * W + w) * C + c] = tile[c][w];
    }
}

// Persistent diagonal LSTM via MFMA (bf16 hi/lo split, ~fp32 accuracy).
// 256 blocks = 32 pg x 8 og, 512 threads = 8 waves; wave = (ch-quad, slot-half) tile.
// K = 384 = [x | h_shift | h]; 12 chunks x 3 split-products of 16x16x32 bf16 MFMA.
// Output rows ordered ch*4+gate so each lane's 4 accums = the 4 gates of one (slot,ch).
__global__ __launch_bounds__(512, 2) void lstm_mfma(
        const float* __restrict__ xT,
        const float* __restrict__ w_is, const float* __restrict__ b_is,
        const float* __restrict__ w_ss, const float* __restrict__ b_ss,
        float* __restrict__ hist, unsigned int* __restrict__ flags) {

    __shared__ short vhi[48 * VSL * 8];   // [kgroup 48][slot 33(pad)][8 bf16] hi
    __shared__ short vlo[48 * VSL * 8];   // lo residual

    const int tid  = threadIdx.x;
    const int og   = blockIdx.x & 7;
    const int pg   = blockIdx.x >> 3;
    const int pgm1 = (pg + 31) & 31;
    const int wave = tid >> 6;
    const int l    = tid & 63;
    const int ct   = wave >> 1;          // ch-quad 0..3
    const int colhalf = wave & 1;        // slot half

    // ---- A-fragments (weights) into VGPRs, bf16 hi/lo ----
    const int rtile = l & 15;            // tile row = ch_local*4 + gate
    const int chl   = rtile >> 2;
    const int gate  = rtile & 3;
    const int khi   = l >> 4;            // k-subgroup 0..3
    const int co_a  = og * 16 + ct * 4 + chl;
    const int wrow  = gate * 128 + co_a;

    bf16x8 Ah[12], Al[12];
#pragma unroll
    for (int cc = 0; cc < 12; ++cc) {
#pragma unroll
        for (int j = 0; j < 8; ++j) {
            const int k = cc * 32 + khi * 8 + j;
            float val;
            if (k < 128)      val = w_is[wrow * 128 + k];
            else if (k < 256) val = w_ss[(wrow * 128 + (k - 128)) * 2 + 0];
            else              val = w_ss[(wrow * 128 + (k - 256)) * 2 + 1];
            const unsigned uv = __float_as_uint(val);
            Ah[cc][j] = (short)(uv >> 16);
            const float r = val - __uint_as_float(uv & 0xffff0000u);
            Al[cc][j] = (short)(__float_as_uint(r) >> 16);
        }
    }

    // ---- per-lane output identity: (slot, ch); c-state in register ----
    const int slot = (l & 15) + colhalf * 16;
    const int bO   = slot >> 1;
    const int rowO = pg + 32 * (slot & 1);
    const int chO  = og * 16 + ct * 4 + khi;
    float creg = 0.f;
    f32x4 bias;
#pragma unroll
    for (int g = 0; g < 4; ++g) bias[g] = b_is[g * 128 + chO] + b_ss[g * 128 + chO];

    // staging k-group indices (depend only on lane)
    const int lm   = (l < 32) ? l : (l - 32);
    const int kq_s = (lm >> 1) & 3;
    const int j0_s = (lm & 1) * 4;
    const int ccx  = lm >> 3;            // x: chunks 0..3 (l<32)
    const int cch  = 8 + (lm >> 3);      // h_prev: chunks 8..11 (l<32)
    const int ccs  = 4 + (lm >> 3);      // h_shift: chunks 4..7 (l>=32)

#pragma unroll 1
    for (int t = 0; t < T; ++t) {
        const bool any = ((unsigned)(t - pg) < 64u) | ((unsigned)(t - pg - 32) < 64u);

        // ---- prefetch x (no flag dependency) ----
        float4 xr[4];
        if (any) {
#pragma unroll
            for (int i = 0; i < 4; ++i) {
                const int s   = wave * 4 + i;
                const int row = pg + 32 * (s & 1);
                const int w   = t - row;
                xr[i] = make_float4(0.f, 0.f, 0.f, 0.f);
                if ((unsigned)w < 64u && l < 32) {
                    const int b = s >> 1;
                    xr[i] = *(const float4*)&xT[((size_t)((b * H + row) * W) + w) * C + l * 4];
                }
            }
        }

        // ---- wait: parallel poll of 16 single-writer flags ----
        if (any && t > 0) {
            if (tid < 16) {
                const int qg = (tid < 8) ? pg : pgm1;
                const unsigned fidx = (unsigned)(qg * 8 + (tid & 7)) * 32u;
                while (__hip_atomic_load(&flags[fidx], __ATOMIC_RELAXED,
                                         __HIP_MEMORY_SCOPE_AGENT) < (unsigned)t) {}
            }
        }
        __syncthreads();   // S1

        // ---- stage v (bf16 hi/lo): wave stages slots wave*4 .. wave*4+3 ----
        if (any) {
#pragma unroll
            for (int i = 0; i < 4; ++i) {
                const int s   = wave * 4 + i;
                const int row = pg + 32 * (s & 1);
                const int w   = t - row;
                if ((unsigned)w < 64u) {
                    const int b = s >> 1;
                    const size_t posbase = ((size_t)((b * H + row) * W) + w) * C;
                    if (l < 32) {
                        stw(vhi, vlo, ((ccx * 4 + kq_s) * VSL + s) * 8 + j0_s, xr[i]);
                        float4 hv = make_float4(0.f, 0.f, 0.f, 0.f);
                        if (w > 0) hv = ld_h16(&hist[posbase - C + l * 4]);
                        stw(vhi, vlo, ((cch * 4 + kq_s) * VSL + s) * 8 + j0_s, hv);
                    } else {
                        float4 hs = make_float4(0.f, 0.f, 0.f, 0.f);
                        if (row > 0)
                            hs = ld_h16(&hist[((size_t)((b * H + row - 1) * W) + w) * C + lm * 4]);
                        stw(vhi, vlo, ((ccs * 4 + kq_s) * VSL + s) * 8 + j0_s, hs);
                    }
                }
            }
        }
        __syncthreads();   // S2

        // ---- MFMA: 12 chunks x (AhBh + AlBh + AhBl) ----
        if (any) {
            f32x4 acc = bias;
#pragma unroll
            for (int cc = 0; cc < 12; ++cc) {
                const int base = ((cc * 4 + khi) * VSL + slot) * 8;
                const bf16x8 Bh = *(const bf16x8*)&vhi[base];
                const bf16x8 Bl = *(const bf16x8*)&vlo[base];
                acc = __builtin_amdgcn_mfma_f32_16x16x32_bf16(Ah[cc], Bh, acc, 0, 0, 0);
                acc = __builtin_amdgcn_mfma_f32_16x16x32_bf16(Al[cc], Bh, acc, 0, 0, 0);
                acc = __builtin_amdgcn_mfma_f32_16x16x32_bf16(Ah[cc], Bl, acc, 0, 0, 0);
            }
            if ((unsigned)(t - rowO) < 64u) {
                const int w = t - rowO;
                const size_t posbase = ((size_t)((bO * H + rowO) * W) + w) * C;
                const float o_ = 1.f / (1.f + __expf(-acc[0]));
                const float f_ = 1.f / (1.f + __expf(-acc[1]));
                const float i_ = 1.f / (1.f + __expf(-acc[2]));
                const float g_ = tanhf(acc[3]);
                creg = f_ * creg + i_ * g_;
                const float hn = o_ * tanhf(creg);
                __hip_atomic_store(&hist[posbase + chO], hn,
                                   __ATOMIC_RELAXED, __HIP_MEMORY_SCOPE_AGENT);
            }
        }
        __syncthreads();   // S3: h stores drained (vmcnt(0) before barrier)
        if (tid == 0)
            __hip_atomic_store(&flags[(unsigned)(pg * 8 + og) * 32u], (unsigned)(t + 1),
                               __ATOMIC_RELAXED, __HIP_MEMORY_SCOPE_AGENT);
    }
}

// hist [B][H][W][C] -> out [B][C][H][W]
__global__ void unhist(const float* __restrict__ hist, float* __restrict__ out) {
    __shared__ float tile[W][C + 1];
    int b = blockIdx.x >> 6, row = blockIdx.x & 63;
    int tid = threadIdx.x;
#pragma unroll
    for (int i = 0; i < (C * W) / 256; ++i) {
        int idx = i * 256 + tid;
        int w = idx >> 7, c = idx & 127;
        tile[w][c] = hist[((size_t)(b * H + row) * W + w) * C + c];
    }
    __syncthreads();
#pragma unroll
    for (int i = 0; i < (C * W) / 256; ++i) {
        int idx = i * 256 + tid;
        int c = idx >> 6, w = idx & 63;
        out[((size_t)(b * C + c) * H + row) * W + w] = tile[w][c];
    }
}

} // namespace

extern "C" void kernel_launch(void* const* d_in, const int* in_sizes, int n_in,
                              void* d_out, int out_size, void* d_ws, size_t ws_size,
                              hipStream_t stream) {
    const float* x    = (const float*)d_in[0];
    const float* w_is = (const float*)d_in[1];
    const float* b_is = (const float*)d_in[2];
    const float* w_ss = (const float*)d_in[3];
    const float* b_ss = (const float*)d_in[4];
    float* out = (float*)d_out;

    float* wsf  = (float*)d_ws;
    float* xT   = wsf;                                  // B*H*W*C floats
    float* hist = xT + (size_t)B * H * W * C;           // B*H*W*C floats
    unsigned int* flags = (unsigned int*)(hist + (size_t)B * H * W * C);  // 256*32 u32

    hipLaunchKernelGGL(transpose_x, dim3(B * H), dim3(256), 0, stream, x, xT);
    hipMemsetAsync(flags, 0, 256 * 32 * sizeof(unsigned int), stream);

    void* args[] = { (void*)&xT, (void*)&w_is, (void*)&b_is, (void*)&w_ss,
                     (void*)&b_ss, (void*)&hist, (void*)&flags };
    hipLaunchCooperativeKernel((const void*)lstm_mfma, dim3(256), dim3(512),
                               args, 0, stream);

    hipLaunchKernelGGL(unhist, dim3(B * H), dim3(256), 0, stream, hist, out);
}